// Round 6
// baseline (116.012 us; speedup 1.0000x reference)
//
#include <hip/hip_runtime.h>

constexpr int B   = 1024;
constexpr int T   = 8192;
constexpr int MS  = 128;
constexpr int NF4 = T / 2;     // 4096 float4 positions per row (2 t's each)

// Padded LDS index for prefix entry k (k in [0, 4096]):
// idx(k) = k + (k>>4). For k = 16*tid + j (j<16) this is 17*tid + j.
__device__ __forceinline__ int pidx(int k) { return k + (k >> 4); }

// Fully fused: one block (256 threads = 4 waves) per batch row, plus
// last-block-done global reduction (deterministic: fixed-order arithmetic,
// single writer of d_out).
// Phase 1: thread tid loads its contiguous 32-t chunk (16 float4) and builds
//          the exclusive per-float4 prefix in registers.
// Phase 2: in-wave __shfl_up scan + cross-wave fixup -> 2-t-granularity
//          exclusive prefix E2[0..4096] in LDS.
// Phase 3: segment sum = E2[e>>1] - E2[s>>1] with <=2 element fixups.
// Phase 4: block reduce -> partial[b] = (nll, cnt, bce_b, 0).
// Phase 5: release fence + atomic ticket; last block acquires and reduces
//          all partials -> out[0].
__global__ __launch_bounds__(256) void provence_fused_kernel(
    const float* __restrict__ rlogits,   // [B]
    const float* __restrict__ rlabels,   // [B]
    const float* __restrict__ logits,    // [B, T, 2]
    const int*   __restrict__ labels,    // [B, MS]
    const int*   __restrict__ bnd,       // [B, MS, 2]
    float4*      __restrict__ partial,   // [B] (nll, cnt, bce, 0)
    unsigned int* __restrict__ counter,  // zeroed via hipMemsetAsync per call
    float*       __restrict__ out)       // [1]
{
    const int b    = blockIdx.x;
    const int tid  = threadIdx.x;
    const int lane = tid & 63;
    const int wave = tid >> 6;
    const float* row = logits + (size_t)b * T * 2;

    __shared__ float2 E2[NF4 + (NF4 >> 4) + 2];   // ~34.9 KB
    __shared__ float  wtot0[4], wtot1[4];
    __shared__ float  rn[4], rc[4], rb[4];
    __shared__ bool   isLast;

    // ---- Phase 0: prefetch metadata; thread 0 computes this row's BCE term --
    int s_ = -1, e_ = -1, lab_ = 0;
    if (tid < MS) {
        const size_t bm = (size_t)b * MS + tid;
        s_   = bnd[bm * 2 + 0];
        e_   = bnd[bm * 2 + 1];
        lab_ = labels[bm];
    }
    float bce_b = 0.f;
    if (tid == 0) {
        const float x = rlogits[b];
        const float y = rlabels[b];
        const float t = log1pf(expf(-fabsf(x)));
        bce_b = y * (fmaxf(-x, 0.f) + t) + (1.f - y) * (fmaxf(x, 0.f) + t);
    }

    // ---- Phase 1: load chunk, build exclusive per-float4 prefix ----
    float4 v[16];
    {
        const float4* p = reinterpret_cast<const float4*>(row) + (size_t)tid * 16;
        #pragma unroll
        for (int j = 0; j < 16; ++j) v[j] = p[j];
    }
    __builtin_amdgcn_sched_barrier(0);   // all 16 loads issued before compute
    float2 exv[16];
    float ex0 = 0.f, ex1 = 0.f;
    #pragma unroll
    for (int j = 0; j < 16; ++j) {
        exv[j] = make_float2(ex0, ex1);            // exclusive prefix at float4 j
        ex0 += v[j].x + v[j].z;
        ex1 += v[j].y + v[j].w;
    }

    // ---- Phase 2: scan of thread totals -> exclusive base; fill E2 ----
    float x0 = ex0, x1 = ex1;
    #pragma unroll
    for (int off = 1; off < 64; off <<= 1) {
        float y0 = __shfl_up(x0, off, 64);
        float y1 = __shfl_up(x1, off, 64);
        if (lane >= off) { x0 += y0; x1 += y1; }
    }
    if (lane == 63) { wtot0[wave] = x0; wtot1[wave] = x1; }
    __syncthreads();
    float pre0 = 0.f, pre1 = 0.f;
    #pragma unroll
    for (int w = 0; w < 3; ++w) {
        if (wave > w) { pre0 += wtot0[w]; pre1 += wtot1[w]; }
    }
    const float incl0 = x0 + pre0,    incl1 = x1 + pre1;
    const float excl0 = incl0 - ex0,  excl1 = incl1 - ex1;
    #pragma unroll
    for (int j = 0; j < 16; ++j) {
        E2[17 * tid + j] = make_float2(excl0 + exv[j].x, excl1 + exv[j].y);
    }
    if (tid == 255) E2[pidx(NF4)] = make_float2(incl0, incl1);  // k = 4096
    __syncthreads();

    // ---- Phase 3: per-segment NLL (parallel over 128 segments) ----
    float nll = 0.f, cnt = 0.f;
    if (tid < MS && s_ != -1) {
        const int sc = min(max(s_, 0), T);
        const int ec = min(max(e_, 0), T);
        const int cs = sc >> 1;
        const int ce = ec >> 1;

        const float2 Ps = E2[pidx(cs)];
        const float2 Pe = E2[pidx(ce)];
        float q0 = Pe.x - Ps.x;
        float q1 = Pe.y - Ps.y;
        if (sc & 1) {  // subtract element sc-1
            float2 u = *reinterpret_cast<const float2*>(row + (size_t)(sc - 1) * 2);
            q0 -= u.x; q1 -= u.y;
        }
        if (ec & 1) {  // add element ec-1
            float2 u = *reinterpret_cast<const float2*>(row + (size_t)(ec - 1) * 2);
            q0 += u.x; q1 += u.y;
        }

        const int len = ec - sc;
        float p0 = 0.f, p1 = 0.f;
        if (len > 0) {
            const float inv = 1.0f / (float)len;
            p0 = q0 * inv;
            p1 = q1 * inv;
        }
        const float mx  = fmaxf(p0, p1);
        const float lse = mx + logf(expf(p0 - mx) + expf(p1 - mx));
        nll = lse - ((lab_ == 0) ? p0 : p1);
        cnt = 1.0f;
    }

    // ---- Phase 4: block reduce -> partial[b] ----
    #pragma unroll
    for (int off = 32; off > 0; off >>= 1) {
        nll += __shfl_down(nll, off, 64);
        cnt += __shfl_down(cnt, off, 64);
    }
    if (lane == 0) { rn[wave] = nll; rc[wave] = cnt; }
    __syncthreads();
    if (tid == 0) {
        partial[b] = make_float4(rn[0] + rn[1] + rn[2] + rn[3],
                                 rc[0] + rc[1] + rc[2] + rc[3],
                                 bce_b, 0.f);
    }

    // ---- Phase 5: last-block-done global reduce ----
    __threadfence();                       // release partial[b]
    if (tid == 0) {
        const unsigned int old = atomicAdd(counter, 1u);
        isLast = (old == (unsigned int)(gridDim.x - 1));
    }
    __syncthreads();
    if (!isLast) return;
    __threadfence();                       // acquire all partials

    float fn = 0.f, fc = 0.f, fb = 0.f;
    #pragma unroll
    for (int i = 0; i < 4; ++i) {
        const float4 p = partial[tid + i * 256];
        fn += p.x; fc += p.y; fb += p.z;
    }
    #pragma unroll
    for (int off = 32; off > 0; off >>= 1) {
        fn += __shfl_down(fn, off, 64);
        fc += __shfl_down(fc, off, 64);
        fb += __shfl_down(fb, off, 64);
    }
    if (lane == 0) { rn[wave] = fn; rc[wave] = fc; rb[wave] = fb; }
    __syncthreads();
    if (tid == 0) {
        const float tn = rn[0] + rn[1] + rn[2] + rn[3];
        const float tc = rc[0] + rc[1] + rc[2] + rc[3];
        const float tb = rb[0] + rb[1] + rb[2] + rb[3];
        const float rank  = tb / (float)B;
        const float prune = (tc > 0.f) ? (tn / tc) : 0.f;
        out[0] = 1.0f * rank + 0.5f * prune;
    }
}

extern "C" void kernel_launch(void* const* d_in, const int* in_sizes, int n_in,
                              void* d_out, int out_size, void* d_ws, size_t ws_size,
                              hipStream_t stream) {
    const float* rlogits = (const float*)d_in[0];  // ranking_logits [B]
    const float* rlabels = (const float*)d_in[1];  // ranking_labels [B]
    const float* plogits = (const float*)d_in[2];  // pruning_logits [B,T,C]
    const int*   plabels = (const int*)  d_in[3];  // pruning_labels [B,MS]
    const int*   bnd     = (const int*)  d_in[4];  // boundaries [B,MS,2]

    float*  out     = (float*)d_out;
    float4* partial = (float4*)d_ws;                       // B float4s
    unsigned int* counter =
        (unsigned int*)((char*)d_ws + (size_t)B * sizeof(float4));

    // Counter must be 0 at kernel start on EVERY call (first call sees
    // uninitialized d_ws; replays must not inherit state).
    hipMemsetAsync(counter, 0, sizeof(unsigned int), stream);

    provence_fused_kernel<<<B, 256, 0, stream>>>(
        rlogits, rlabels, plogits, plabels, bnd, partial, counter, out);
}

// Round 7
// 19.637 us; speedup vs baseline: 5.9078x; 5.9078x over previous
//
#include <hip/hip_runtime.h>

constexpr int B   = 1024;
constexpr int T   = 8192;
constexpr int MS  = 128;
constexpr int NF4 = T / 2;     // 4096 float4 positions per row (2 t's each)

// Padded LDS index for prefix entry k (k in [0, 4096]):
// idx(k) = k + (k>>4). For k = 16*tid + j (j<16) this is 17*tid + j.
__device__ __forceinline__ int pidx(int k) { return k + (k >> 4); }

// One block (256 threads = 4 waves) per batch row.
// __launch_bounds__(256,4): cap occupancy assumption at 4 waves/EU so the
// allocator grants ~128 VGPRs -> all 16 float4 loads live in registers
// (round-6 post-mortem: default allocation chose 52 VGPRs and spilled).
// Phase 1: thread tid loads its contiguous 32-t chunk (16 float4), sums it.
// Phase 2: in-wave __shfl_up scan + cross-wave fixup -> 2-t-granularity
//          exclusive prefix E2[0..4096] in LDS (prefix recomputed from v[]
//          during the write loop -- no exv[] array, saves 32 VGPRs).
// Phase 3: segment sum = E2[e>>1] - E2[s>>1] with <=2 element fixups.
// Phase 4: block reduce -> partial[b] = (nll, cnt, bce_b, 0).
__global__ __launch_bounds__(256, 4) void seg_loss_kernel(
    const float* __restrict__ rlogits,   // [B]
    const float* __restrict__ rlabels,   // [B]
    const float* __restrict__ logits,    // [B, T, 2]
    const int*   __restrict__ labels,    // [B, MS]
    const int*   __restrict__ bnd,       // [B, MS, 2]
    float4*      __restrict__ partial)   // [B] (nll, cnt, bce, 0)
{
    const int b    = blockIdx.x;
    const int tid  = threadIdx.x;
    const int lane = tid & 63;
    const int wave = tid >> 6;
    const float* row = logits + (size_t)b * T * 2;

    __shared__ float2 E2[NF4 + (NF4 >> 4) + 2];   // ~34.9 KB
    __shared__ float  wtot0[4], wtot1[4];
    __shared__ float  rn[4], rc[4];

    // ---- Phase 0: metadata; thread 0 computes this row's BCE term ----
    int s_ = -1, e_ = -1, lab_ = 0;
    if (tid < MS) {
        const size_t bm = (size_t)b * MS + tid;
        s_   = bnd[bm * 2 + 0];
        e_   = bnd[bm * 2 + 1];
        lab_ = labels[bm];
    }
    float bce_b = 0.f;
    if (tid == 0) {
        const float x = rlogits[b];
        const float y = rlabels[b];
        const float t = log1pf(expf(-fabsf(x)));
        bce_b = y * (fmaxf(-x, 0.f) + t) + (1.f - y) * (fmaxf(x, 0.f) + t);
    }

    // ---- Phase 1: batch-load chunk (16 float4 in flight), then sum ----
    float4 v[16];
    {
        const float4* p = reinterpret_cast<const float4*>(row) + (size_t)tid * 16;
        #pragma unroll
        for (int j = 0; j < 16; ++j) v[j] = p[j];
    }
    __builtin_amdgcn_sched_barrier(0);   // all 16 loads issued before compute
    float ex0 = 0.f, ex1 = 0.f;
    #pragma unroll
    for (int j = 0; j < 16; ++j) {
        ex0 += v[j].x + v[j].z;
        ex1 += v[j].y + v[j].w;
    }

    // ---- Phase 2: scan of thread totals -> exclusive base; fill E2 ----
    float x0 = ex0, x1 = ex1;
    #pragma unroll
    for (int off = 1; off < 64; off <<= 1) {
        float y0 = __shfl_up(x0, off, 64);
        float y1 = __shfl_up(x1, off, 64);
        if (lane >= off) { x0 += y0; x1 += y1; }
    }
    if (lane == 63) { wtot0[wave] = x0; wtot1[wave] = x1; }
    __syncthreads();
    float pre0 = 0.f, pre1 = 0.f;
    #pragma unroll
    for (int w = 0; w < 3; ++w) {
        if (wave > w) { pre0 += wtot0[w]; pre1 += wtot1[w]; }
    }
    const float incl0 = x0 + pre0,    incl1 = x1 + pre1;
    float run0 = incl0 - ex0, run1 = incl1 - ex1;   // exclusive base
    #pragma unroll
    for (int j = 0; j < 16; ++j) {                  // recompute prefix from v[]
        E2[17 * tid + j] = make_float2(run0, run1);
        run0 += v[j].x + v[j].z;
        run1 += v[j].y + v[j].w;
    }
    if (tid == 255) E2[pidx(NF4)] = make_float2(run0, run1);  // k = 4096
    __syncthreads();

    // ---- Phase 3: per-segment NLL (parallel over 128 segments) ----
    float nll = 0.f, cnt = 0.f;
    if (tid < MS && s_ != -1) {
        const int sc = min(max(s_, 0), T);
        const int ec = min(max(e_, 0), T);
        const int cs = sc >> 1;
        const int ce = ec >> 1;

        const float2 Ps = E2[pidx(cs)];
        const float2 Pe = E2[pidx(ce)];
        float q0 = Pe.x - Ps.x;
        float q1 = Pe.y - Ps.y;
        if (sc & 1) {  // subtract element sc-1
            float2 u = *reinterpret_cast<const float2*>(row + (size_t)(sc - 1) * 2);
            q0 -= u.x; q1 -= u.y;
        }
        if (ec & 1) {  // add element ec-1
            float2 u = *reinterpret_cast<const float2*>(row + (size_t)(ec - 1) * 2);
            q0 += u.x; q1 += u.y;
        }

        const int len = ec - sc;
        float p0 = 0.f, p1 = 0.f;
        if (len > 0) {
            const float inv = 1.0f / (float)len;
            p0 = q0 * inv;
            p1 = q1 * inv;
        }
        const float mx  = fmaxf(p0, p1);
        const float lse = mx + logf(expf(p0 - mx) + expf(p1 - mx));
        nll = lse - ((lab_ == 0) ? p0 : p1);
        cnt = 1.0f;
    }

    // ---- Phase 4: block reduce -> partial[b] ----
    #pragma unroll
    for (int off = 32; off > 0; off >>= 1) {
        nll += __shfl_down(nll, off, 64);
        cnt += __shfl_down(cnt, off, 64);
    }
    if (lane == 0) { rn[wave] = nll; rc[wave] = cnt; }
    __syncthreads();
    if (tid == 0) {
        partial[b] = make_float4(rn[0] + rn[1] + rn[2] + rn[3],
                                 rc[0] + rc[1] + rc[2] + rc[3],
                                 bce_b, 0.f);
    }
}

// Single-block finalize: reduce per-row partials (nll, cnt, bce) -> scalar.
__global__ __launch_bounds__(256) void finalize_kernel(
    const float4* __restrict__ partial,  // [B]
    float*        __restrict__ out)      // [1]
{
    const int tid  = threadIdx.x;
    const int lane = tid & 63;
    const int wave = tid >> 6;

    float nll = 0.f, cnt = 0.f, bce = 0.f;
    #pragma unroll
    for (int i = 0; i < 4; ++i) {
        const float4 p = partial[tid + i * 256];
        nll += p.x; cnt += p.y; bce += p.z;
    }

    #pragma unroll
    for (int off = 32; off > 0; off >>= 1) {
        nll += __shfl_down(nll, off, 64);
        cnt += __shfl_down(cnt, off, 64);
        bce += __shfl_down(bce, off, 64);
    }
    __shared__ float sn[4], sc[4], sb[4];
    if (lane == 0) { sn[wave] = nll; sc[wave] = cnt; sb[wave] = bce; }
    __syncthreads();
    if (tid == 0) {
        const float tn = sn[0] + sn[1] + sn[2] + sn[3];
        const float tc = sc[0] + sc[1] + sc[2] + sc[3];
        const float tb = sb[0] + sb[1] + sb[2] + sb[3];
        const float rank  = tb / (float)B;
        const float prune = (tc > 0.f) ? (tn / tc) : 0.f;
        out[0] = 1.0f * rank + 0.5f * prune;
    }
}

extern "C" void kernel_launch(void* const* d_in, const int* in_sizes, int n_in,
                              void* d_out, int out_size, void* d_ws, size_t ws_size,
                              hipStream_t stream) {
    const float* rlogits = (const float*)d_in[0];  // ranking_logits [B]
    const float* rlabels = (const float*)d_in[1];  // ranking_labels [B]
    const float* plogits = (const float*)d_in[2];  // pruning_logits [B,T,C]
    const int*   plabels = (const int*)  d_in[3];  // pruning_labels [B,MS]
    const int*   bnd     = (const int*)  d_in[4];  // boundaries [B,MS,2]

    float*  out     = (float*)d_out;
    float4* partial = (float4*)d_ws;   // B float4s, fully written by kernel 1

    seg_loss_kernel<<<B, 256, 0, stream>>>(rlogits, rlabels, plogits,
                                           plabels, bnd, partial);
    finalize_kernel<<<1, 256, 0, stream>>>(partial, out);
}